// Round 9
// baseline (332.931 us; speedup 1.0000x reference)
//
#include <hip/hip_runtime.h>

typedef _Float16 f16;
typedef _Float16 f16x8 __attribute__((ext_vector_type(8)));
typedef _Float16 f16x4 __attribute__((ext_vector_type(4)));
typedef float v4f __attribute__((ext_vector_type(4)));

constexpr int H = 512, W = 512, NB = 8;
constexpr int ROWS = 514;               // padded rows
constexpr int COLS = 528;               // px p at col p+8
constexpr int CH = 8;
constexpr size_t ROWBYTES = (size_t)COLS * CH * 2;        // 8448
constexpr size_t PLANE_ELEMS = (size_t)ROWS * COLS * CH;
constexpr size_t PLANE_BYTES = PLANE_ELEMS * 2;

constexpr int RSP = 145;                // 128px-tile LDS row stride (final/conv1 kernels)
constexpr int RSPC = RSP * CH;
constexpr int LDS_ROWB = RSP * 16;
constexpr int WTAB_L = 3072;

// fused kernel (64px tiles): row = 80 px + 1 pad = 81 px * 16B = 1296 B
constexpr int FRSP = 81;
constexpr int FRSPC = FRSP * CH;        // 648 f16
constexpr int FROWB = FRSP * 16;        // 1296 B
constexpr int INR = 21;                 // input ring rows
constexpr int ARR = 18;                 // A-ring rows

__device__ __forceinline__ void gload_lds16(const void* g, void* l) {
    __builtin_amdgcn_global_load_lds(
        (const __attribute__((address_space(1))) unsigned int*)g,
        (__attribute__((address_space(3))) unsigned int*)l, 16, 0, 0);
}
__device__ __forceinline__ void gload_lds4(const void* g, void* l) {
    __builtin_amdgcn_global_load_lds(
        (const __attribute__((address_space(1))) unsigned int*)g,
        (__attribute__((address_space(3))) unsigned int*)l, 4, 0, 0);
}

// ---------------- zero borders of the 2 plane-sets ----------------------------
__global__ void zero_borders(f16* __restrict__ base, size_t set_stride) {
    const int i = blockIdx.x * 256 + threadIdx.x;
    if (i >= 9248) return;
    const int img = blockIdx.y, set = blockIdx.z;
    int row, col;
    if (i < 1056) { row = (i < 528) ? 0 : 513; col = (i < 528) ? i : i - 528; }
    else {
        const int j = i - 1056;
        row = 1 + (j >> 4);
        const int c4 = j & 15;
        col = (c4 < 8) ? c4 : 512 + c4;
    }
    f16x8 z = {};
    f16* p = base + (size_t)set * set_stride + ((size_t)img * ROWS + row) * COLS * CH + (size_t)col * CH;
    *(f16x8*)p = z;
}

// ---------------- precompute per-lane weight fragments (19 layers) ------------
__global__ void build_wtab(const float* __restrict__ wmid,
                           const float* __restrict__ w20,
                           f16* __restrict__ wtab) {
    const int l = blockIdx.x;
    const int lane = threadIdx.x;
    const float* wt = (l < 18) ? wmid + (size_t)l * 576 : w20;
    const int COUT = (l < 18) ? 8 : 1;
    const int n = lane & 15, q = lane >> 4;
#pragma unroll
    for (int g = 0; g < 3; ++g) {
        const int t = g * 4 + q;
        f16x8 hv, lv;
#pragma unroll
        for (int j = 0; j < 8; ++j) {
            float wv = 0.f;
            if (n < 8) {
                if (t <= 8 && n < COUT) wv = wt[(n * 8 + j) * 9 + t];
            } else {
                const int o = n - 8;
                if (t >= 3 && o < COUT) wv = wt[(o * 8 + j) * 9 + (t - 3)];
            }
            const f16 h = (f16)wv;
            hv[j] = h;
            lv[j] = (f16)(wv - (float)h);
        }
        f16* dst = wtab + (size_t)l * WTAB_L + (g * 2) * 512 + lane * 8;
        *(f16x8*)dst = hv;
        *(f16x8*)(dst + 512) = lv;
    }
}

// ---------------- conv1: 1->8 + relu ------------------------------------------
__global__ __launch_bounds__(256) void conv1_kernel(
    const float* __restrict__ in, const float* __restrict__ wt,
    f16* __restrict__ out)
{
    const int x0 = (blockIdx.x * 64 + threadIdx.x) * 4;
    const int y  = blockIdx.y * 4 + threadIdx.y;
    const int b  = blockIdx.z;
    const float* inb = in + (size_t)b * H * W;

    float patch[3][6];
#pragma unroll
    for (int r = 0; r < 3; ++r) {
        const int iy = y - 1 + r;
        if (iy >= 0 && iy < H) {
            const float* rp = inb + (size_t)iy * W;
            const float4 v = *(const float4*)(rp + x0);
            patch[r][1] = v.x; patch[r][2] = v.y; patch[r][3] = v.z; patch[r][4] = v.w;
            patch[r][0] = (x0 > 0)     ? rp[x0 - 1] : 0.f;
            patch[r][5] = (x0 + 4 < W) ? rp[x0 + 4] : 0.f;
        } else {
#pragma unroll
            for (int k = 0; k < 6; ++k) patch[r][k] = 0.f;
        }
    }

    float acc[8][4];
#pragma unroll
    for (int o = 0; o < 8; ++o) {
        const float* wo = wt + o * 9;
        float a0 = 0.f, a1 = 0.f, a2 = 0.f, a3 = 0.f;
#pragma unroll
        for (int r = 0; r < 3; ++r)
#pragma unroll
            for (int k = 0; k < 3; ++k) {
                const float wv = wo[r * 3 + k];
                a0 = fmaf(wv, patch[r][k + 0], a0);
                a1 = fmaf(wv, patch[r][k + 1], a1);
                a2 = fmaf(wv, patch[r][k + 2], a2);
                a3 = fmaf(wv, patch[r][k + 3], a3);
            }
        acc[o][0] = a0; acc[o][1] = a1; acc[o][2] = a2; acc[o][3] = a3;
    }

#pragma unroll
    for (int j = 0; j < 4; ++j) {
        f16x8 hv;
#pragma unroll
        for (int o = 0; o < 8; ++o)
            hv[o] = (f16)fmaxf(acc[o][j], 0.f);
        const size_t off = (((size_t)b * ROWS + (y + 1)) * COLS + (x0 + j + 8)) * CH;
        *(f16x8*)(out + off) = hv;
    }
}

// ---------------- FUSED 2-layer conv, region-pipelined ------------------------
// Block 256 = 4 waves; grid (img, 8 x-tiles of 64px, 8 chunks of 64 rows).
// A leads B by one full strip. Region t (one barrier at end):
//   stage input for A(t+2)  [DMA, consumed next region]
//   compute A-batch t+1     [reads inring (staged last region), writes aring]
//   compute B strip t       [reads aring (written last region), writes global]
// inring 21 rows / aring 18 rows; slot reuse only touches rows whose readers
// finished before the previous barrier (analysis in session notes).
__global__ __launch_bounds__(256) void conv2fused(
    const f16* __restrict__ in,
    const f16* __restrict__ wtA, const f16* __restrict__ wtB,
    f16* __restrict__ outp)
{
    // aring FIRST: A-phase halo reads at inring col -1 land in aring tail
    // (defined garbage feeding unused A cols), never out of the shared block.
    __shared__ __align__(16) f16 aring[ARR * FRSPC];   // 23328 B
    __shared__ __align__(16) f16 inring[INR * FRSPC];  // 27216 B

    const int wave = threadIdx.x >> 6, lane = threadIdx.x & 63;
    const int img = blockIdx.x, xt = blockIdx.y;
    const int x0 = xt * 64;
    const int base = blockIdx.z * 64;   // B outputs padded rows base+1..base+64

    f16x8 ahiW[3], aloW[3], bhiW[3], bloW[3];
#pragma unroll
    for (int g = 0; g < 3; ++g) {
        const f16* wa = wtA + (g * 2) * 512 + lane * 8;
        ahiW[g] = *(const f16x8*)wa;  aloW[g] = *(const f16x8*)(wa + 512);
        const f16* wb = wtB + (g * 2) * 512 + lane * 8;
        bhiW[g] = *(const f16x8*)wb;  bloW[g] = *(const f16x8*)(wb + 512);
    }

    // global src at px x0-8 (padded col x0)
    const char* src = (const char*)in + (size_t)img * PLANE_BYTES + (size_t)x0 * 16;

    // stage padded rows [r0, r0+cnt), clamped to [0,513], slot = row mod 21
    auto stage = [&](int r0, int cnt) {
        for (int rr = wave; rr < cnt; rr += 4) {
            const int row = r0 + rr;
            const int rowc = min(max(row, 0), 513);
            const int slot = ((row % INR) + INR) % INR;
            const char* gs = src + (size_t)rowc * ROWBYTES;
            char* ld = (char*)inring + slot * FROWB;
            gload_lds16(gs + lane * 16, ld);                       // 1024 B
            if (lane < 16) gload_lds16(gs + 1024 + lane * 16, ld + 1024);  // 256 B
        }
    };

    const int n = lane & 15, q = lane >> 4;
    int tyv[3], txv[3];
#pragma unroll
    for (int g = 0; g < 3; ++g) { const int t = g * 4 + q; tyv[g] = t / 3 - 1; txv[g] = t % 3 - 1; }
    const int rowoff = q >> 1, choff = (q & 1) * 4;
    const bool xe0 = (xt == 0), xe7 = (xt == 7);

    // A-phase: rows (rA, rA+1); A cols c=16s+n (s=0..4), px = x0-8+c -> aring
    auto computeA = [&](int rA) {
        int irow[3];
#pragma unroll
        for (int g = 0; g < 3; ++g) {
            const int r = rA + tyv[g];
            irow[g] = (((r % INR) + INR) % INR) * FRSPC;
        }
        const int gyA = rA + rowoff;
        const int wrow = (gyA % ARR) * FRSPC;
        const bool zr = (gyA == 0) || (gyA == 513);
#pragma unroll
        for (int s = 0; s < 5; ++s) {
            v4f acc = {0.f,0.f,0.f,0.f}, acc2 = {0.f,0.f,0.f,0.f};
#pragma unroll
            for (int g = 0; g < 3; ++g) {
                const f16x8 xv = *(const f16x8*)&inring[irow[g] + (16 * s + n + txv[g]) * CH];
                acc  = __builtin_amdgcn_mfma_f32_16x16x32_f16(ahiW[g], xv, acc,  0, 0, 0);
                acc2 = __builtin_amdgcn_mfma_f32_16x16x32_f16(aloW[g], xv, acc2, 0, 0, 0);
            }
            const v4f res = acc + acc2;
            f16x4 hv;
#pragma unroll
            for (int c = 0; c < 4; ++c) hv[c] = (f16)fmaxf(res[c], 0.f);
            // SAME-pad for B: zero at global borders (rows 0/513; px -1 at
            // xt==0 -> col 7 (s0,n7); px 512 at xt==7 -> col 72 (s4,n8))
            if (zr || (xe0 && s == 0 && n == 7) || (xe7 && s == 4 && n == 8)) {
                hv[0] = (f16)0.f; hv[1] = (f16)0.f; hv[2] = (f16)0.f; hv[3] = (f16)0.f;
            }
            *(f16x4*)&aring[wrow + (16 * s + n) * CH + choff] = hv;
        }
    };

    // B-phase: rows (rB, rB+1); B px = x0+16s+n (s=0..3) -> global
    auto computeB = [&](int rB) {
        int brow[3];
#pragma unroll
        for (int g = 0; g < 3; ++g) brow[g] = ((rB + tyv[g]) % ARR) * FRSPC;
        const int gyB = rB + rowoff;
        f16* orow = outp + ((size_t)img * ROWS + gyB) * COLS * CH + (size_t)(x0 + 8) * CH + choff;
#pragma unroll
        for (int s = 0; s < 4; ++s) {
            v4f acc = {0.f,0.f,0.f,0.f}, acc2 = {0.f,0.f,0.f,0.f};
#pragma unroll
            for (int g = 0; g < 3; ++g) {
                const f16x8 xv = *(const f16x8*)&aring[brow[g] + (16 * s + n + txv[g] + 8) * CH];
                acc  = __builtin_amdgcn_mfma_f32_16x16x32_f16(bhiW[g], xv, acc,  0, 0, 0);
                acc2 = __builtin_amdgcn_mfma_f32_16x16x32_f16(bloW[g], xv, acc2, 0, 0, 0);
            }
            const v4f res = acc + acc2;
            f16x4 hv;
#pragma unroll
            for (int c = 0; c < 4; ++c) hv[c] = (f16)fmaxf(res[c], 0.f);
            *(f16x4*)(orow + (size_t)(16 * s + n) * CH) = hv;
        }
    };

    // ---- prime: input rows base-1..base+19 (21); A rows base..base+9 ----
    stage(base - 1, 21);
    __syncthreads();                     // staging visible
    for (int p = wave; p < 5; p += 4) computeA(base + 2 * p);
    __syncthreads();                     // prime-A visible

    for (int t = 0; t < 8; ++t) {
        if (t < 6) stage(base + 8 * t + 20, 8);        // for A(t+2)
        if (t < 7) computeA(base + 8 * t + 10 + 2 * wave);  // A-batch t+1
        computeB(base + 8 * t + 1 + 2 * wave);         // B strip t
        __syncthreads();
    }
}

// ---------------- final conv (128px pipelined, r7 structure) ------------------
template<bool RELU, bool FINAL>
__global__ __launch_bounds__(256) void convmfma(
    const f16* __restrict__ in, const f16* __restrict__ wtab_l,
    f16* __restrict__ outp, float* __restrict__ out_final)
{
    __shared__ __align__(16) f16 lds[2][10 * RSPC];

    const int wave = threadIdx.x >> 6, lane = threadIdx.x & 63;
    const int img = blockIdx.x;
    const int x0 = blockIdx.y * 128;
    const int ybase = blockIdx.z * 32;

    f16x8 bhi[3], blo[3];
#pragma unroll
    for (int g = 0; g < 3; ++g) {
        const f16* wp = wtab_l + (g * 2) * 512 + lane * 8;
        bhi[g] = *(const f16x8*)wp;
        blo[g] = *(const f16x8*)(wp + 512);
    }

    const char* src = (const char*)in + (size_t)img * PLANE_BYTES + (size_t)x0 * 16;
    auto stage = [&](int buf, int y0) {
        char* dst = (char*)&lds[buf][0];
        for (int qq = wave; qq < 30; qq += 4) {
            const int r = qq / 3, c = qq % 3;
            const char* gs = src + (size_t)(y0 + r) * ROWBYTES;
            char* ld = dst + r * LDS_ROWB;
            if (c < 2) gload_lds16(gs + c * 1024 + lane * 16, ld + c * 1024);
            else       gload_lds4(gs + 2048 + lane * 4, ld + 2048);
        }
    };

    const int n = lane & 15, q = lane >> 4, m = lane & 15;
    int abase[3];
#pragma unroll
    for (int g = 0; g < 3; ++g) {
        const int t = g * 4 + q;
        const int ty = t / 3 - 1, tx = t % 3 - 1;
        abase[g] = (2 * wave + ty + 1) * RSP + (m + tx + 8);
    }
    const int rowoff = q >> 1;
    const int choff = (q & 1) * 4;

    stage(0, ybase);
    __syncthreads();

    for (int t = 0; t < 4; ++t) {
        if (t < 3) stage((t + 1) & 1, ybase + 8 * (t + 1));
        const f16* L = &lds[t & 1][0];
        const int Y = ybase + 8 * t + 2 * wave;
#pragma unroll
        for (int s = 0; s < 8; ++s) {
            v4f acc = {0.f,0.f,0.f,0.f}, acc2 = {0.f,0.f,0.f,0.f};
#pragma unroll
            for (int g = 0; g < 3; ++g) {
                const f16x8 xv = *(const f16x8*)&L[(abase[g] + 16 * s) * CH];
                acc  = __builtin_amdgcn_mfma_f32_16x16x32_f16(bhi[g], xv, acc,  0, 0, 0);
                acc2 = __builtin_amdgcn_mfma_f32_16x16x32_f16(blo[g], xv, acc2, 0, 0, 0);
            }
            const v4f res = acc + acc2;
            if constexpr (!FINAL) {
                f16x4 hv;
#pragma unroll
                for (int c = 0; c < 4; ++c) {
                    float v = res[c];
                    if (RELU) v = fmaxf(v, 0.f);
                    hv[c] = (f16)v;
                }
                const int gy = Y + rowoff + 1;
                const int gx = x0 + 16 * s + n + 8;
                *(f16x4*)(outp + ((size_t)img * ROWS + gy) * COLS * CH + (size_t)gx * CH + choff) = hv;
            } else {
                if ((q & 1) == 0) {
                    const int gy = Y + rowoff, gx = x0 + 16 * s + n;
                    out_final[((size_t)img * H + gy) * W + gx] = res[0];
                }
            }
        }
        if (t < 3) __syncthreads();
    }
}

extern "C" void kernel_launch(void* const* d_in, const int* in_sizes, int n_in,
                              void* d_out, int out_size, void* d_ws, size_t ws_size,
                              hipStream_t stream) {
    const float* x    = (const float*)d_in[0];
    const float* w1   = (const float*)d_in[1];
    const float* wmid = (const float*)d_in[2];
    const float* w20  = (const float*)d_in[3];
    float* out = (float*)d_out;

    const size_t wtab_bytes = (size_t)19 * WTAB_L * 2;
    int g = NB;
    while (g > 1 && 2 * (size_t)g * PLANE_BYTES + wtab_bytes > ws_size) g >>= 1;

    f16* act0 = (f16*)d_ws;
    f16* act1 = act0 + (size_t)g * PLANE_ELEMS;
    f16* wtab = act1 + (size_t)g * PLANE_ELEMS;

    zero_borders<<<dim3(37, g, 2), 256, 0, stream>>>(act0, (size_t)g * PLANE_ELEMS);
    build_wtab<<<19, 64, 0, stream>>>(wmid, w20, wtab);

    for (int b0 = 0; b0 < NB; b0 += g) {
        conv1_kernel<<<dim3(2, 128, g), dim3(64, 4), 0, stream>>>(
            x + (size_t)b0 * H * W, w1, act0);
        for (int k = 0; k < 9; ++k) {
            const f16* s0 = (k & 1) ? act1 : act0;
            f16*       d0 = (k & 1) ? act0 : act1;
            conv2fused<<<dim3(g, 8, 8), 256, 0, stream>>>(
                s0, wtab + (size_t)(2 * k) * WTAB_L, wtab + (size_t)(2 * k + 1) * WTAB_L, d0);
        }
        convmfma<false, true><<<dim3(g, 4, 16), 256, 0, stream>>>(
            act1, wtab + (size_t)18 * WTAB_L, nullptr, out + (size_t)b0 * H * W);
    }
}

// Round 10
// 270.889 us; speedup vs baseline: 1.2290x; 1.2290x over previous
//
#include <hip/hip_runtime.h>

typedef _Float16 f16;
typedef _Float16 f16x8 __attribute__((ext_vector_type(8)));
typedef _Float16 f16x4 __attribute__((ext_vector_type(4)));
typedef float v4f __attribute__((ext_vector_type(4)));

constexpr int H = 512, W = 512, NB = 8;
constexpr int ROWS = 514;               // padded rows
constexpr int COLS = 528;               // px p at col p+8
constexpr int CH = 8;
constexpr size_t ROWBYTES = (size_t)COLS * CH * 2;        // 8448
constexpr size_t PLANE_ELEMS = (size_t)ROWS * COLS * CH;
constexpr size_t PLANE_BYTES = PLANE_ELEMS * 2;

constexpr int RSP = 145;                // 128px-tile LDS row stride (final/conv1)
constexpr int RSPC = RSP * CH;
constexpr int LDS_ROWB = RSP * 16;
constexpr int WTAB_L = 3072;

// fused kernel (64px tiles): row = 80 px + 1 pad = 81 px * 16B = 1296 B
constexpr int FRSP = 81;
constexpr int FRSPC = FRSP * CH;        // 648 f16
constexpr int FROWB = FRSP * 16;        // 1296 B
constexpr int INR = 12;                 // input ring rows (r8 schedule, minimal)
constexpr int ARR = 10;                 // A-ring rows

__device__ __forceinline__ void gload_lds16(const void* g, void* l) {
    __builtin_amdgcn_global_load_lds(
        (const __attribute__((address_space(1))) unsigned int*)g,
        (__attribute__((address_space(3))) unsigned int*)l, 16, 0, 0);
}
__device__ __forceinline__ void gload_lds4(const void* g, void* l) {
    __builtin_amdgcn_global_load_lds(
        (const __attribute__((address_space(1))) unsigned int*)g,
        (__attribute__((address_space(3))) unsigned int*)l, 4, 0, 0);
}

// ---------------- zero borders of the 2 plane-sets ----------------------------
__global__ void zero_borders(f16* __restrict__ base, size_t set_stride) {
    const int i = blockIdx.x * 256 + threadIdx.x;
    if (i >= 9248) return;
    const int img = blockIdx.y, set = blockIdx.z;
    int row, col;
    if (i < 1056) { row = (i < 528) ? 0 : 513; col = (i < 528) ? i : i - 528; }
    else {
        const int j = i - 1056;
        row = 1 + (j >> 4);
        const int c4 = j & 15;
        col = (c4 < 8) ? c4 : 512 + c4;
    }
    f16x8 z = {};
    f16* p = base + (size_t)set * set_stride + ((size_t)img * ROWS + row) * COLS * CH + (size_t)col * CH;
    *(f16x8*)p = z;
}

// ---------------- precompute per-lane weight fragments (19 layers) ------------
__global__ void build_wtab(const float* __restrict__ wmid,
                           const float* __restrict__ w20,
                           f16* __restrict__ wtab) {
    const int l = blockIdx.x;
    const int lane = threadIdx.x;
    const float* wt = (l < 18) ? wmid + (size_t)l * 576 : w20;
    const int COUT = (l < 18) ? 8 : 1;
    const int n = lane & 15, q = lane >> 4;
#pragma unroll
    for (int g = 0; g < 3; ++g) {
        const int t = g * 4 + q;
        f16x8 hv, lv;
#pragma unroll
        for (int j = 0; j < 8; ++j) {
            float wv = 0.f;
            if (n < 8) {
                if (t <= 8 && n < COUT) wv = wt[(n * 8 + j) * 9 + t];
            } else {
                const int o = n - 8;
                if (t >= 3 && o < COUT) wv = wt[(o * 8 + j) * 9 + (t - 3)];
            }
            const f16 h = (f16)wv;
            hv[j] = h;
            lv[j] = (f16)(wv - (float)h);
        }
        f16* dst = wtab + (size_t)l * WTAB_L + (g * 2) * 512 + lane * 8;
        *(f16x8*)dst = hv;
        *(f16x8*)(dst + 512) = lv;
    }
}

// ---------------- conv1: 1->8 + relu ------------------------------------------
__global__ __launch_bounds__(256) void conv1_kernel(
    const float* __restrict__ in, const float* __restrict__ wt,
    f16* __restrict__ out)
{
    const int x0 = (blockIdx.x * 64 + threadIdx.x) * 4;
    const int y  = blockIdx.y * 4 + threadIdx.y;
    const int b  = blockIdx.z;
    const float* inb = in + (size_t)b * H * W;

    float patch[3][6];
#pragma unroll
    for (int r = 0; r < 3; ++r) {
        const int iy = y - 1 + r;
        if (iy >= 0 && iy < H) {
            const float* rp = inb + (size_t)iy * W;
            const float4 v = *(const float4*)(rp + x0);
            patch[r][1] = v.x; patch[r][2] = v.y; patch[r][3] = v.z; patch[r][4] = v.w;
            patch[r][0] = (x0 > 0)     ? rp[x0 - 1] : 0.f;
            patch[r][5] = (x0 + 4 < W) ? rp[x0 + 4] : 0.f;
        } else {
#pragma unroll
            for (int k = 0; k < 6; ++k) patch[r][k] = 0.f;
        }
    }

    float acc[8][4];
#pragma unroll
    for (int o = 0; o < 8; ++o) {
        const float* wo = wt + o * 9;
        float a0 = 0.f, a1 = 0.f, a2 = 0.f, a3 = 0.f;
#pragma unroll
        for (int r = 0; r < 3; ++r)
#pragma unroll
            for (int k = 0; k < 3; ++k) {
                const float wv = wo[r * 3 + k];
                a0 = fmaf(wv, patch[r][k + 0], a0);
                a1 = fmaf(wv, patch[r][k + 1], a1);
                a2 = fmaf(wv, patch[r][k + 2], a2);
                a3 = fmaf(wv, patch[r][k + 3], a3);
            }
        acc[o][0] = a0; acc[o][1] = a1; acc[o][2] = a2; acc[o][3] = a3;
    }

#pragma unroll
    for (int j = 0; j < 4; ++j) {
        f16x8 hv;
#pragma unroll
        for (int o = 0; o < 8; ++o)
            hv[o] = (f16)fmaxf(acc[o][j], 0.f);
        const size_t off = (((size_t)b * ROWS + (y + 1)) * COLS + (x0 + j + 8)) * CH;
        *(f16x8*)(out + off) = hv;
    }
}

// ---------------- FUSED 2-layer conv, r8 schedule at 4 blocks/CU --------------
// Block 256 = 4 waves; grid (img, 8 x-tiles of 64px, 16 chunks of 32 rows)
// = 1024 blocks -> 4 blocks/CU, 4 waves/SIMD: independent blocks interleave
// across each other's barrier stalls (the barrier's vmcnt(0) drain is
// structural -- __syncthreads drains all DMA -- so hide it with TLP, not
// scheduling). Per strip t: computeA(t) -> barrier -> stage(t+1) + computeB(t)
// -> barrier. inring 12 rows / aring 10 rows (slot liveness: 10 consecutive
// rows live in each ring at any instant; distinct mod ring size).
__global__ __launch_bounds__(256, 4) void conv2fused(
    const f16* __restrict__ in,
    const f16* __restrict__ wtA, const f16* __restrict__ wtB,
    f16* __restrict__ outp)
{
    // aring FIRST: A-phase halo reads at inring col -1 (feeding only the
    // unused A output col 0) land in aring's tail, inside the shared block.
    __shared__ __align__(16) f16 aring[ARR * FRSPC];   // 12960 B
    __shared__ __align__(16) f16 inring[INR * FRSPC];  // 15552 B

    const int wave = threadIdx.x >> 6, lane = threadIdx.x & 63;
    const int img = blockIdx.x, xt = blockIdx.y;
    const int x0 = xt * 64;
    const int base = blockIdx.z * 32;   // B outputs padded rows base+1..base+32

    f16x8 ahiW[3], aloW[3], bhiW[3], bloW[3];
#pragma unroll
    for (int g = 0; g < 3; ++g) {
        const f16* wa = wtA + (g * 2) * 512 + lane * 8;
        ahiW[g] = *(const f16x8*)wa;  aloW[g] = *(const f16x8*)(wa + 512);
        const f16* wb = wtB + (g * 2) * 512 + lane * 8;
        bhiW[g] = *(const f16x8*)wb;  bloW[g] = *(const f16x8*)(wb + 512);
    }

    // global src at px x0-8 (padded col x0); rows are 80px = 1280 B
    const char* src = (const char*)in + (size_t)img * PLANE_BYTES + (size_t)x0 * 16;

    // stage padded rows [r0, r0+cnt), clamped to [0,513], slot = row mod 12
    auto stage = [&](int r0, int cnt) {
        for (int rr = wave; rr < cnt; rr += 4) {
            const int row = r0 + rr;
            const int rowc = min(max(row, 0), 513);
            const int slot = ((row % INR) + INR) % INR;
            const char* gs = src + (size_t)rowc * ROWBYTES;
            char* ld = (char*)inring + slot * FROWB;
            gload_lds16(gs + lane * 16, ld);                                // 1024 B
            if (lane < 16) gload_lds16(gs + 1024 + lane * 16, ld + 1024);   // 256 B
        }
    };

    const int n = lane & 15, q = lane >> 4;
    int tyv[3], txv[3];
#pragma unroll
    for (int g = 0; g < 3; ++g) { const int t = g * 4 + q; tyv[g] = t / 3 - 1; txv[g] = t % 3 - 1; }
    const int rowoff = q >> 1, choff = (q & 1) * 4;
    const bool xe0 = (xt == 0), xe7 = (xt == 7);

    // A-phase: rows (rA, rA+1); A cols c=16s+n (s=0..4), px = x0-8+c -> aring
    auto computeA = [&](int rA) {
        int irow[3];
#pragma unroll
        for (int g = 0; g < 3; ++g) {
            const int r = rA + tyv[g];
            irow[g] = (((r % INR) + INR) % INR) * FRSPC;
        }
        const int gyA = rA + rowoff;
        const int wrow = (gyA % ARR) * FRSPC;
        const bool zr = (gyA == 0) || (gyA == 513);
#pragma unroll
        for (int s = 0; s < 5; ++s) {
            v4f acc = {0.f,0.f,0.f,0.f}, acc2 = {0.f,0.f,0.f,0.f};
#pragma unroll
            for (int g = 0; g < 3; ++g) {
                const f16x8 xv = *(const f16x8*)&inring[irow[g] + (16 * s + n + txv[g]) * CH];
                acc  = __builtin_amdgcn_mfma_f32_16x16x32_f16(ahiW[g], xv, acc,  0, 0, 0);
                acc2 = __builtin_amdgcn_mfma_f32_16x16x32_f16(aloW[g], xv, acc2, 0, 0, 0);
            }
            const v4f res = acc + acc2;
            f16x4 hv;
#pragma unroll
            for (int c = 0; c < 4; ++c) hv[c] = (f16)fmaxf(res[c], 0.f);
            // SAME-pad for B: zero at global borders (rows 0/513; px -1 at
            // xt==0 -> col 7 (s0,n7); px 512 at xt==7 -> col 72 (s4,n8))
            if (zr || (xe0 && s == 0 && n == 7) || (xe7 && s == 4 && n == 8)) {
                hv[0] = (f16)0.f; hv[1] = (f16)0.f; hv[2] = (f16)0.f; hv[3] = (f16)0.f;
            }
            *(f16x4*)&aring[wrow + (16 * s + n) * CH + choff] = hv;
        }
    };

    // B-phase: rows (rB, rB+1); B px = x0+16s+n (s=0..3) -> global
    auto computeB = [&](int rB) {
        int brow[3];
#pragma unroll
        for (int g = 0; g < 3; ++g) brow[g] = ((rB + tyv[g]) % ARR) * FRSPC;
        const int gyB = rB + rowoff;
        f16* orow = outp + ((size_t)img * ROWS + gyB) * COLS * CH + (size_t)(x0 + 8) * CH + choff;
#pragma unroll
        for (int s = 0; s < 4; ++s) {
            v4f acc = {0.f,0.f,0.f,0.f}, acc2 = {0.f,0.f,0.f,0.f};
#pragma unroll
            for (int g = 0; g < 3; ++g) {
                const f16x8 xv = *(const f16x8*)&aring[brow[g] + (16 * s + n + txv[g] + 8) * CH];
                acc  = __builtin_amdgcn_mfma_f32_16x16x32_f16(bhiW[g], xv, acc,  0, 0, 0);
                acc2 = __builtin_amdgcn_mfma_f32_16x16x32_f16(bloW[g], xv, acc2, 0, 0, 0);
            }
            const v4f res = acc + acc2;
            f16x4 hv;
#pragma unroll
            for (int c = 0; c < 4; ++c) hv[c] = (f16)fmaxf(res[c], 0.f);
            *(f16x4*)(orow + (size_t)(16 * s + n) * CH) = hv;
        }
    };

    // ---- prime: input rows base-1..base+10 (12); A pair (base, base+1) ----
    stage(base - 1, 12);
    __syncthreads();
    if (wave == 0) computeA(base);

    for (int t = 0; t < 4; ++t) {
        computeA(base + 8 * t + 2 + 2 * wave);       // A rows [b+8t+2 .. +9]
        __syncthreads();                             // A visible
        if (t < 3) stage(base + 8 * t + 11, 8);      // rows +11..+18 (for A t+1)
        computeB(base + 8 * t + 1 + 2 * wave);       // B rows [b+8t+1 .. +8]
        __syncthreads();                             // drains staging + stores
    }
}

// ---------------- final conv (128px pipelined, r7 structure) ------------------
template<bool RELU, bool FINAL>
__global__ __launch_bounds__(256) void convmfma(
    const f16* __restrict__ in, const f16* __restrict__ wtab_l,
    f16* __restrict__ outp, float* __restrict__ out_final)
{
    __shared__ __align__(16) f16 lds[2][10 * RSPC];

    const int wave = threadIdx.x >> 6, lane = threadIdx.x & 63;
    const int img = blockIdx.x;
    const int x0 = blockIdx.y * 128;
    const int ybase = blockIdx.z * 32;

    f16x8 bhi[3], blo[3];
#pragma unroll
    for (int g = 0; g < 3; ++g) {
        const f16* wp = wtab_l + (g * 2) * 512 + lane * 8;
        bhi[g] = *(const f16x8*)wp;
        blo[g] = *(const f16x8*)(wp + 512);
    }

    const char* src = (const char*)in + (size_t)img * PLANE_BYTES + (size_t)x0 * 16;
    auto stage = [&](int buf, int y0) {
        char* dst = (char*)&lds[buf][0];
        for (int qq = wave; qq < 30; qq += 4) {
            const int r = qq / 3, c = qq % 3;
            const char* gs = src + (size_t)(y0 + r) * ROWBYTES;
            char* ld = dst + r * LDS_ROWB;
            if (c < 2) gload_lds16(gs + c * 1024 + lane * 16, ld + c * 1024);
            else       gload_lds4(gs + 2048 + lane * 4, ld + 2048);
        }
    };

    const int n = lane & 15, q = lane >> 4, m = lane & 15;
    int abase[3];
#pragma unroll
    for (int g = 0; g < 3; ++g) {
        const int t = g * 4 + q;
        const int ty = t / 3 - 1, tx = t % 3 - 1;
        abase[g] = (2 * wave + ty + 1) * RSP + (m + tx + 8);
    }
    const int rowoff = q >> 1;
    const int choff = (q & 1) * 4;

    stage(0, ybase);
    __syncthreads();

    for (int t = 0; t < 4; ++t) {
        if (t < 3) stage((t + 1) & 1, ybase + 8 * (t + 1));
        const f16* L = &lds[t & 1][0];
        const int Y = ybase + 8 * t + 2 * wave;
#pragma unroll
        for (int s = 0; s < 8; ++s) {
            v4f acc = {0.f,0.f,0.f,0.f}, acc2 = {0.f,0.f,0.f,0.f};
#pragma unroll
            for (int g = 0; g < 3; ++g) {
                const f16x8 xv = *(const f16x8*)&L[(abase[g] + 16 * s) * CH];
                acc  = __builtin_amdgcn_mfma_f32_16x16x32_f16(bhi[g], xv, acc,  0, 0, 0);
                acc2 = __builtin_amdgcn_mfma_f32_16x16x32_f16(blo[g], xv, acc2, 0, 0, 0);
            }
            const v4f res = acc + acc2;
            if constexpr (!FINAL) {
                f16x4 hv;
#pragma unroll
                for (int c = 0; c < 4; ++c) {
                    float v = res[c];
                    if (RELU) v = fmaxf(v, 0.f);
                    hv[c] = (f16)v;
                }
                const int gy = Y + rowoff + 1;
                const int gx = x0 + 16 * s + n + 8;
                *(f16x4*)(outp + ((size_t)img * ROWS + gy) * COLS * CH + (size_t)gx * CH + choff) = hv;
            } else {
                if ((q & 1) == 0) {
                    const int gy = Y + rowoff, gx = x0 + 16 * s + n;
                    out_final[((size_t)img * H + gy) * W + gx] = res[0];
                }
            }
        }
        if (t < 3) __syncthreads();
    }
}

extern "C" void kernel_launch(void* const* d_in, const int* in_sizes, int n_in,
                              void* d_out, int out_size, void* d_ws, size_t ws_size,
                              hipStream_t stream) {
    const float* x    = (const float*)d_in[0];
    const float* w1   = (const float*)d_in[1];
    const float* wmid = (const float*)d_in[2];
    const float* w20  = (const float*)d_in[3];
    float* out = (float*)d_out;

    const size_t wtab_bytes = (size_t)19 * WTAB_L * 2;
    int g = NB;
    while (g > 1 && 2 * (size_t)g * PLANE_BYTES + wtab_bytes > ws_size) g >>= 1;

    f16* act0 = (f16*)d_ws;
    f16* act1 = act0 + (size_t)g * PLANE_ELEMS;
    f16* wtab = act1 + (size_t)g * PLANE_ELEMS;

    zero_borders<<<dim3(37, g, 2), 256, 0, stream>>>(act0, (size_t)g * PLANE_ELEMS);
    build_wtab<<<19, 64, 0, stream>>>(wmid, w20, wtab);

    for (int b0 = 0; b0 < NB; b0 += g) {
        conv1_kernel<<<dim3(2, 128, g), dim3(64, 4), 0, stream>>>(
            x + (size_t)b0 * H * W, w1, act0);
        for (int k = 0; k < 9; ++k) {
            const f16* s0 = (k & 1) ? act1 : act0;
            f16*       d0 = (k & 1) ? act0 : act1;
            conv2fused<<<dim3(g, 8, 16), 256, 0, stream>>>(
                s0, wtab + (size_t)(2 * k) * WTAB_L, wtab + (size_t)(2 * k + 1) * WTAB_L, d0);
        }
        convmfma<false, true><<<dim3(g, 4, 16), 256, 0, stream>>>(
            act1, wtab + (size_t)18 * WTAB_L, nullptr, out + (size_t)b0 * H * W);
    }
}